// Round 20
// baseline (82.145 us; speedup 1.0000x reference)
//
#include <hip/hip_runtime.h>

#define IMG_W 1024
#define IMG_H 1024
#define NFRAMES 32
#define CROP 4
#define RPB 32          // 32 bands x 32 frames = 1024 blocks
#define RING 8          // ring slots; single-barrier epochs (overwrite = 2-epochs-old slot)
#define ROWB 4096
#define ABYTES (RING*ROWB)   // 32 KiB per tensor; 64 KiB total -> 2 blocks/CU

__device__ __forceinline__ void gl_lds16(const float* g, void* l) {
    __builtin_amdgcn_global_load_lds(
        (const __attribute__((address_space(1))) void*)g,
        (__attribute__((address_space(3))) void*)l,
        16, 0, 0);
}

__global__ __launch_bounds__(256) void gimbaless_sums(
    const float* __restrict__ A, const float* __restrict__ B,
    const float* __restrict__ lp9, double* __restrict__ sums)
{
    __shared__ __align__(16) unsigned char smem[2 * ABYTES];

    const int tid  = threadIdx.x;
    const int band = (blockIdx.x & 7) * 4 + (blockIdx.x >> 3);   // XCD swizzle (kept)
    const int t    = blockIdx.y;
    const float* a = A + (size_t)t * (IMG_W * IMG_H);
    const float* b = B + (size_t)t * (IMG_W * IMG_H);

    const float lp0 = lp9[0], lp1 = lp9[1], lp2 = lp9[2], lp3 = lp9[3], lp4 = lp9[4];

    const int r0   = CROP + band * RPB;
    const int rend = min(r0 + RPB, IMG_H - CROP);   // even row count

    const int t16 = tid * 16;
    const int wb  = (tid >> 6) * 1024;

    auto stage = [&](int r) {
        const int slot = r & (RING - 1);
        gl_lds16(a + (size_t)r * IMG_W + tid * 4, smem + slot * ROWB + wb);
        gl_lds16(b + (size_t)r * IMG_W + tid * 4, smem + ABYTES + slot * ROWB + wb);
    };
    auto rdA = [&](int slot, int off) -> float4 {
        return *(const float4*)(smem + slot * ROWB + off);
    };
    auto rdB = [&](int slot, int off) -> float4 {
        return *(const float4*)(smem + ABYTES + slot * ROWB + off);
    };

    float s0=0.f,s1=0.f,s2=0.f,s3=0.f,s4=0.f,s5=0.f,s6=0.f,s7=0.f,s8=0.f;
    float d[10][4];   // dif rows h-4 .. h+5
    float av[7][4];   // avg rows h-1 .. h+5
    const bool active = ((unsigned)(tid - 1) < 254u);
    const int w0 = 4 * tid;
    const float x0 = (float)w0 - 511.5f;

    // ---- prologue: stage rows r0-4 .. r0+3 (8 rows = full ring) ----
    for (int r = r0 - 4; r <= r0 + 3; ++r) stage(r);
    asm volatile("s_waitcnt vmcnt(0)" ::: "memory");
    if (active) {
#pragma unroll
        for (int k = 0; k < 8; ++k) {                 // narrow window r0-4..r0+3
            const int slot = (r0 - 4 + k) & (RING - 1);
            float4 va = rdA(slot, t16);
            float4 vb = rdB(slot, t16);
            d[k][0]=va.x-vb.x; d[k][1]=va.y-vb.y; d[k][2]=va.z-vb.z; d[k][3]=va.w-vb.w;
            if (k >= 3) {
                av[k-3][0]=(va.x+vb.x)*0.5f; av[k-3][1]=(va.y+vb.y)*0.5f;
                av[k-3][2]=(va.z+vb.z)*0.5f; av[k-3][3]=(va.w+vb.w)*0.5f;
            }
        }
    }
    asm volatile("s_waitcnt lgkmcnt(0)" ::: "memory");   // prologue reads landed
    stage(r0 + 4); stage(r0 + 5);                        // slots of r0-4, r0-3 (read)

    // ---- main loop: 2 rows per epoch, ONE barrier + ONE vmcnt per epoch ----
#pragma unroll 1
    for (int h = r0; h < rend; h += 2) {
        asm volatile("s_waitcnt vmcnt(0)" ::: "memory");  // rows h+4,h+5 arrived
        __builtin_amdgcn_s_barrier();
        // Orders: (a) h+4,h+5 visible to all waves; (b) every wave finished
        // epoch h-2 (program order), so slots of rows h-2,h-1 are fully read.

        if (h + 2 < rend) { stage(h + 6); stage(h + 7); } // overwrite slots (h+6)%8=(h-2)%8

        const int m0 = h & (RING - 1);
        const int m1 = (h + 1) & (RING - 1);
        const int m4 = (h + 4) & (RING - 1);
        const int m5 = (h + 5) & (RING - 1);

        if (active) {
            float4 na0 = rdA(m4, t16),      nb0 = rdB(m4, t16);
            float4 na1 = rdA(m5, t16),      nb1 = rdB(m5, t16);
            float4 la0 = rdA(m0, t16 - 16), lb0 = rdB(m0, t16 - 16);
            float4 ra0 = rdA(m0, t16 + 16), rb0 = rdB(m0, t16 + 16);
            float4 la1 = rdA(m1, t16 - 16), lb1 = rdB(m1, t16 - 16);
            float4 ra1 = rdA(m1, t16 + 16), rb1 = rdB(m1, t16 + 16);

            d[8][0]=na0.x-nb0.x; d[8][1]=na0.y-nb0.y; d[8][2]=na0.z-nb0.z; d[8][3]=na0.w-nb0.w;
            av[5][0]=(na0.x+nb0.x)*0.5f; av[5][1]=(na0.y+nb0.y)*0.5f;
            av[5][2]=(na0.z+nb0.z)*0.5f; av[5][3]=(na0.w+nb0.w)*0.5f;
            d[9][0]=na1.x-nb1.x; d[9][1]=na1.y-nb1.y; d[9][2]=na1.z-nb1.z; d[9][3]=na1.w-nb1.w;
            av[6][0]=(na1.x+nb1.x)*0.5f; av[6][1]=(na1.y+nb1.y)*0.5f;
            av[6][2]=(na1.z+nb1.z)*0.5f; av[6][3]=(na1.w+nb1.w)*0.5f;

#pragma unroll
            for (int rr = 0; rr < 2; ++rr) {
                float dc[12], avc[6];
                if (rr == 0) {
                    dc[0]=la0.x-lb0.x; dc[1]=la0.y-lb0.y; dc[2]=la0.z-lb0.z; dc[3]=la0.w-lb0.w;
                    dc[4]=d[4][0]; dc[5]=d[4][1]; dc[6]=d[4][2]; dc[7]=d[4][3];
                    dc[8]=ra0.x-rb0.x; dc[9]=ra0.y-rb0.y; dc[10]=ra0.z-rb0.z; dc[11]=ra0.w-rb0.w;
                    avc[0]=(la0.w+lb0.w)*0.5f;
                    avc[1]=av[1][0]; avc[2]=av[1][1]; avc[3]=av[1][2]; avc[4]=av[1][3];
                    avc[5]=(ra0.x+rb0.x)*0.5f;
                } else {
                    dc[0]=la1.x-lb1.x; dc[1]=la1.y-lb1.y; dc[2]=la1.z-lb1.z; dc[3]=la1.w-lb1.w;
                    dc[4]=d[5][0]; dc[5]=d[5][1]; dc[6]=d[5][2]; dc[7]=d[5][3];
                    dc[8]=ra1.x-rb1.x; dc[9]=ra1.y-rb1.y; dc[10]=ra1.z-rb1.z; dc[11]=ra1.w-rb1.w;
                    avc[0]=(la1.w+lb1.w)*0.5f;
                    avc[1]=av[2][0]; avc[2]=av[2][1]; avc[3]=av[2][2]; avc[4]=av[2][3];
                    avc[5]=(ra1.x+rb1.x)*0.5f;
                }
                const float y = (float)(h + rr) - 511.5f;
#pragma unroll
                for (int j = 0; j < 4; ++j) {
                    const float px = (avc[j] - avc[j + 2]) * 0.5f;
                    const float py = (av[rr][j] - av[rr + 2][j]) * 0.5f;
                    float ax = lp4 * dc[j + 4];
                    ax = fmaf(lp0, dc[j] + dc[j + 8], ax);
                    ax = fmaf(lp1, dc[j + 1] + dc[j + 7], ax);
                    ax = fmaf(lp2, dc[j + 2] + dc[j + 6], ax);
                    ax = fmaf(lp3, dc[j + 3] + dc[j + 5], ax);
                    float ay = lp4 * d[rr + 4][j];
                    ay = fmaf(lp0, d[rr][j] + d[rr + 8][j], ay);
                    ay = fmaf(lp1, d[rr + 1][j] + d[rr + 7][j], ay);
                    ay = fmaf(lp2, d[rr + 2][j] + d[rr + 6][j], ay);
                    ay = fmaf(lp3, d[rr + 3][j] + d[rr + 5][j], ay);

                    const float x = x0 + (float)j;
                    const float mom = px * y - py * x;
                    s0 = fmaf(px, px, s0);
                    s1 = fmaf(px, py, s1);
                    s2 = fmaf(px, mom, s2);
                    s3 = fmaf(py, py, s3);
                    s4 = fmaf(py, mom, s4);
                    s5 = fmaf(mom, mom, s5);
                    const float tx = ax * px;
                    const float ty = ay * py;
                    s6 += tx;
                    s7 += ty;
                    s8 += tx * y - ty * x;
                }
            }

#pragma unroll
            for (int k = 0; k < 8; ++k) {
                d[k][0]=d[k+2][0]; d[k][1]=d[k+2][1]; d[k][2]=d[k+2][2]; d[k][3]=d[k+2][3];
            }
#pragma unroll
            for (int k = 0; k < 5; ++k) {
                av[k][0]=av[k+2][0]; av[k][1]=av[k+2][1]; av[k][2]=av[k+2][2]; av[k][3]=av[k+2][3];
            }
        }
    }

    // ---- reduction: f64 wave shuffle -> LDS (aliased) -> global atomic ----
    double ds[9];
    ds[0]=s0; ds[1]=s1; ds[2]=s2; ds[3]=s3; ds[4]=s4;
    ds[5]=s5; ds[6]=s6; ds[7]=s7; ds[8]=s8;
#pragma unroll
    for (int k = 0; k < 9; ++k) {
        double x = ds[k];
        for (int off = 32; off > 0; off >>= 1)
            x += __shfl_down(x, off);
        ds[k] = x;
    }
    __syncthreads();                          // full vm+lgkm drain + barrier
    double (*red)[9] = (double(*)[9])smem;
    const int wave = tid >> 6, lane = tid & 63;
    if (lane == 0) {
#pragma unroll
        for (int k = 0; k < 9; ++k) red[wave][k] = ds[k];
    }
    __syncthreads();
    if (tid < 9) {
        double tot = red[0][tid] + red[1][tid] + red[2][tid] + red[3][tid];
        atomicAdd(&sums[(size_t)t * 9 + tid], tot);
    }
}

__global__ void gimbaless_solve(const double* __restrict__ sums, float* __restrict__ out)
{
    const int t = threadIdx.x;
    if (t < NFRAMES) {
        const double* s = sums + (size_t)t * 9;
        const double m00=s[0], m01=s[1], m02=s[2], m11=s[3], m12=s[4], m22=s[5];
        const double b0=s[6], b1=s[7], b2=s[8];
        const double c00 = m11*m22 - m12*m12;
        const double c01 = m02*m12 - m01*m22;
        const double c02 = m01*m12 - m02*m11;
        const double c11 = m00*m22 - m02*m02;
        const double c12 = m01*m02 - m00*m12;
        const double c22 = m00*m11 - m01*m01;
        const double det = m00*c00 + m01*c01 + m02*c02;
        const double inv = 1.0 / det;
        out[t]             = (float)((c00*b0 + c01*b1 + c02*b2) * inv);
        out[NFRAMES + t]   = (float)((c01*b0 + c11*b1 + c12*b2) * inv);
        out[2*NFRAMES + t] = (float)((c02*b0 + c12*b1 + c22*b2) * inv);
    }
}

extern "C" void kernel_launch(void* const* d_in, const int* in_sizes, int n_in,
                              void* d_out, int out_size, void* d_ws, size_t ws_size,
                              hipStream_t stream) {
    const float* A  = (const float*)d_in[0];
    const float* B  = (const float*)d_in[1];
    const float* lp = (const float*)d_in[2];
    double* sums = (double*)d_ws;

    (void)hipMemsetAsync(d_ws, 0, NFRAMES * 9 * sizeof(double), stream);

    dim3 grid((IMG_H - 2*CROP + RPB - 1) / RPB, NFRAMES);  // (32, 32)
    gimbaless_sums<<<grid, 256, 0, stream>>>(A, B, lp, sums);
    gimbaless_solve<<<1, 64, 0, stream>>>(sums, (float*)d_out);
}

// Round 21
// 80.496 us; speedup vs baseline: 1.0205x; 1.0205x over previous
//
#include <hip/hip_runtime.h>

#define IMG_W 1024
#define IMG_H 1024
#define NFRAMES 32
#define CROP 4
#define RPB 32          // 32 bands x 32 frames = 1024 blocks
#define NBANDS 32
#define RING 6          // block-shared LDS ring slots (full 4KB rows)
#define ROWB 4096
#define ABYTES (RING*ROWB)   // 24 KiB per tensor; total 48 KiB -> 3 blocks/CU

__device__ __forceinline__ void gl_lds16(const float* g, void* l) {
    __builtin_amdgcn_global_load_lds(
        (const __attribute__((address_space(1))) void*)g,
        (__attribute__((address_space(3))) void*)l,
        16, 0, 0);
}

template<int USE_PARTIALS>
__global__ __launch_bounds__(256) void gimbaless_sums(
    const float* __restrict__ A, const float* __restrict__ B,
    const float* __restrict__ lp9, double* __restrict__ sums)
{
    __shared__ __align__(16) unsigned char smem[2 * ABYTES];

    const int tid  = threadIdx.x;
    const int band = (blockIdx.x & 7) * 4 + (blockIdx.x >> 3);   // XCD swizzle
    const int t    = blockIdx.y;
    const float* a = A + (size_t)t * (IMG_W * IMG_H);
    const float* b = B + (size_t)t * (IMG_W * IMG_H);

    const float lp0 = lp9[0], lp1 = lp9[1], lp2 = lp9[2], lp3 = lp9[3], lp4 = lp9[4];

    const int r0   = CROP + band * RPB;
    const int rend = min(r0 + RPB, IMG_H - CROP);   // even row count

    const int t16 = tid * 16;
    const int wb  = (tid >> 6) * 1024;

    auto stage = [&](int r) {
        const int slot = r % RING;
        gl_lds16(a + (size_t)r * IMG_W + tid * 4, smem + slot * ROWB + wb);
        gl_lds16(b + (size_t)r * IMG_W + tid * 4, smem + ABYTES + slot * ROWB + wb);
    };
    auto rdA = [&](int slot, int off) -> float4 {
        return *(const float4*)(smem + slot * ROWB + off);
    };
    auto rdB = [&](int slot, int off) -> float4 {
        return *(const float4*)(smem + ABYTES + slot * ROWB + off);
    };

    float s0=0.f,s1=0.f,s2=0.f,s3=0.f,s4=0.f,s5=0.f,s6=0.f,s7=0.f,s8=0.f;
    float d[10][4];   // dif rows h-4 .. h+5
    float av[7][4];   // avg rows h-1 .. h+5
    const bool active = ((unsigned)(tid - 1) < 254u);
    const int w0 = 4 * tid;
    const float x0 = (float)w0 - 511.5f;

    // ---- prologue ----
    for (int r = r0 - 4; r <= r0 + 1; ++r) stage(r);
    asm volatile("s_waitcnt vmcnt(0)" ::: "memory");
    if (active) {
#pragma unroll
        for (int k = 0; k < 6; ++k) {
            const int slot = (r0 - 4 + k) % RING;
            float4 va = rdA(slot, t16);
            float4 vb = rdB(slot, t16);
            d[k][0]=va.x-vb.x; d[k][1]=va.y-vb.y; d[k][2]=va.z-vb.z; d[k][3]=va.w-vb.w;
            if (k >= 3) {
                av[k-3][0]=(va.x+vb.x)*0.5f; av[k-3][1]=(va.y+vb.y)*0.5f;
                av[k-3][2]=(va.z+vb.z)*0.5f; av[k-3][3]=(va.w+vb.w)*0.5f;
            }
        }
    }
    asm volatile("s_waitcnt lgkmcnt(0)" ::: "memory");
    stage(r0 + 2); stage(r0 + 3); stage(r0 + 4); stage(r0 + 5);
    asm volatile("s_waitcnt vmcnt(4)" ::: "memory");
    if (active) {
#pragma unroll
        for (int k = 6; k < 8; ++k) {
            const int slot = (r0 - 4 + k) % RING;
            float4 va = rdA(slot, t16);
            float4 vb = rdB(slot, t16);
            d[k][0]=va.x-vb.x; d[k][1]=va.y-vb.y; d[k][2]=va.z-vb.z; d[k][3]=va.w-vb.w;
            av[k-3][0]=(va.x+vb.x)*0.5f; av[k-3][1]=(va.y+vb.y)*0.5f;
            av[k-3][2]=(va.z+vb.z)*0.5f; av[k-3][3]=(va.w+vb.w)*0.5f;
        }
    }

    // ---- main loop: 2 rows per epoch ----
#pragma unroll 1
    for (int h = r0; h < rend; h += 2) {
        asm volatile("s_waitcnt vmcnt(0)" ::: "memory");
        __builtin_amdgcn_s_barrier();

        const int m0 = h % RING;
        const int m1 = (h + 1) % RING;
        const int m4 = (h + 4) % RING;
        const int m5 = (h + 5) % RING;

        float4 na0, nb0, na1, nb1, la0, lb0, ra0, rb0, la1, lb1, ra1, rb1;
        if (active) {
            na0 = rdA(m4, t16);      nb0 = rdB(m4, t16);
            na1 = rdA(m5, t16);      nb1 = rdB(m5, t16);
            la0 = rdA(m0, t16 - 16); lb0 = rdB(m0, t16 - 16);
            ra0 = rdA(m0, t16 + 16); rb0 = rdB(m0, t16 + 16);
            la1 = rdA(m1, t16 - 16); lb1 = rdB(m1, t16 - 16);
            ra1 = rdA(m1, t16 + 16); rb1 = rdB(m1, t16 + 16);
        }
        asm volatile("s_waitcnt lgkmcnt(0)" ::: "memory");
        __builtin_amdgcn_s_barrier();

        if (h + 2 < rend) { stage(h + 6); stage(h + 7); }

        if (active) {
            d[8][0]=na0.x-nb0.x; d[8][1]=na0.y-nb0.y; d[8][2]=na0.z-nb0.z; d[8][3]=na0.w-nb0.w;
            av[5][0]=(na0.x+nb0.x)*0.5f; av[5][1]=(na0.y+nb0.y)*0.5f;
            av[5][2]=(na0.z+nb0.z)*0.5f; av[5][3]=(na0.w+nb0.w)*0.5f;
            d[9][0]=na1.x-nb1.x; d[9][1]=na1.y-nb1.y; d[9][2]=na1.z-nb1.z; d[9][3]=na1.w-nb1.w;
            av[6][0]=(na1.x+nb1.x)*0.5f; av[6][1]=(na1.y+nb1.y)*0.5f;
            av[6][2]=(na1.z+nb1.z)*0.5f; av[6][3]=(na1.w+nb1.w)*0.5f;

#pragma unroll
            for (int rr = 0; rr < 2; ++rr) {
                float dc[12], avc[6];
                if (rr == 0) {
                    dc[0]=la0.x-lb0.x; dc[1]=la0.y-lb0.y; dc[2]=la0.z-lb0.z; dc[3]=la0.w-lb0.w;
                    dc[4]=d[4][0]; dc[5]=d[4][1]; dc[6]=d[4][2]; dc[7]=d[4][3];
                    dc[8]=ra0.x-rb0.x; dc[9]=ra0.y-rb0.y; dc[10]=ra0.z-rb0.z; dc[11]=ra0.w-rb0.w;
                    avc[0]=(la0.w+lb0.w)*0.5f;
                    avc[1]=av[1][0]; avc[2]=av[1][1]; avc[3]=av[1][2]; avc[4]=av[1][3];
                    avc[5]=(ra0.x+rb0.x)*0.5f;
                } else {
                    dc[0]=la1.x-lb1.x; dc[1]=la1.y-lb1.y; dc[2]=la1.z-lb1.z; dc[3]=la1.w-lb1.w;
                    dc[4]=d[5][0]; dc[5]=d[5][1]; dc[6]=d[5][2]; dc[7]=d[5][3];
                    dc[8]=ra1.x-rb1.x; dc[9]=ra1.y-rb1.y; dc[10]=ra1.z-rb1.z; dc[11]=ra1.w-rb1.w;
                    avc[0]=(la1.w+lb1.w)*0.5f;
                    avc[1]=av[2][0]; avc[2]=av[2][1]; avc[3]=av[2][2]; avc[4]=av[2][3];
                    avc[5]=(ra1.x+rb1.x)*0.5f;
                }
                const float y = (float)(h + rr) - 511.5f;
#pragma unroll
                for (int j = 0; j < 4; ++j) {
                    const float px = (avc[j] - avc[j + 2]) * 0.5f;
                    const float py = (av[rr][j] - av[rr + 2][j]) * 0.5f;
                    float ax = lp4 * dc[j + 4];
                    ax = fmaf(lp0, dc[j] + dc[j + 8], ax);
                    ax = fmaf(lp1, dc[j + 1] + dc[j + 7], ax);
                    ax = fmaf(lp2, dc[j + 2] + dc[j + 6], ax);
                    ax = fmaf(lp3, dc[j + 3] + dc[j + 5], ax);
                    float ay = lp4 * d[rr + 4][j];
                    ay = fmaf(lp0, d[rr][j] + d[rr + 8][j], ay);
                    ay = fmaf(lp1, d[rr + 1][j] + d[rr + 7][j], ay);
                    ay = fmaf(lp2, d[rr + 2][j] + d[rr + 6][j], ay);
                    ay = fmaf(lp3, d[rr + 3][j] + d[rr + 5][j], ay);

                    const float x = x0 + (float)j;
                    const float mom = px * y - py * x;
                    s0 = fmaf(px, px, s0);
                    s1 = fmaf(px, py, s1);
                    s2 = fmaf(px, mom, s2);
                    s3 = fmaf(py, py, s3);
                    s4 = fmaf(py, mom, s4);
                    s5 = fmaf(mom, mom, s5);
                    const float tx = ax * px;
                    const float ty = ay * py;
                    s6 += tx;
                    s7 += ty;
                    s8 += tx * y - ty * x;
                }
            }

#pragma unroll
            for (int k = 0; k < 8; ++k) {
                d[k][0]=d[k+2][0]; d[k][1]=d[k+2][1]; d[k][2]=d[k+2][2]; d[k][3]=d[k+2][3];
            }
#pragma unroll
            for (int k = 0; k < 5; ++k) {
                av[k][0]=av[k+2][0]; av[k][1]=av[k+2][1]; av[k][2]=av[k+2][2]; av[k][3]=av[k+2][3];
            }
        }
    }

    // ---- reduction: f64 wave shuffle -> LDS (aliased) -> partial write / atomic ----
    double ds[9];
    ds[0]=s0; ds[1]=s1; ds[2]=s2; ds[3]=s3; ds[4]=s4;
    ds[5]=s5; ds[6]=s6; ds[7]=s7; ds[8]=s8;
#pragma unroll
    for (int k = 0; k < 9; ++k) {
        double x = ds[k];
        for (int off = 32; off > 0; off >>= 1)
            x += __shfl_down(x, off);
        ds[k] = x;
    }
    __syncthreads();
    double (*red)[9] = (double(*)[9])smem;
    const int wave = tid >> 6, lane = tid & 63;
    if (lane == 0) {
#pragma unroll
        for (int k = 0; k < 9; ++k) red[wave][k] = ds[k];
    }
    __syncthreads();
    if (tid < 9) {
        double tot = red[0][tid] + red[1][tid] + red[2][tid] + red[3][tid];
        if (USE_PARTIALS) {
            // no memset needed: every (t, blockIdx.x, k) slot written exactly once
            sums[((size_t)t * NBANDS + blockIdx.x) * 9 + tid] = tot;
        } else {
            atomicAdd(&sums[(size_t)t * 9 + tid], tot);
        }
    }
}

template<int USE_PARTIALS>
__global__ void gimbaless_solve(const double* __restrict__ sums, float* __restrict__ out)
{
    const int t = threadIdx.x;
    if (t < NFRAMES) {
        double m[9];
        if (USE_PARTIALS) {
#pragma unroll
            for (int k = 0; k < 9; ++k) m[k] = 0.0;
            const double* p = sums + (size_t)t * NBANDS * 9;
            for (int bnd = 0; bnd < NBANDS; ++bnd)
#pragma unroll
                for (int k = 0; k < 9; ++k) m[k] += p[bnd * 9 + k];
        } else {
#pragma unroll
            for (int k = 0; k < 9; ++k) m[k] = sums[(size_t)t * 9 + k];
        }
        const double m00=m[0], m01=m[1], m02=m[2], m11=m[3], m12=m[4], m22=m[5];
        const double b0=m[6], b1=m[7], b2=m[8];
        const double c00 = m11*m22 - m12*m12;
        const double c01 = m02*m12 - m01*m22;
        const double c02 = m01*m12 - m02*m11;
        const double c11 = m00*m22 - m02*m02;
        const double c12 = m01*m02 - m00*m12;
        const double c22 = m00*m11 - m01*m01;
        const double det = m00*c00 + m01*c01 + m02*c02;
        const double inv = 1.0 / det;
        out[t]             = (float)((c00*b0 + c01*b1 + c02*b2) * inv);
        out[NFRAMES + t]   = (float)((c01*b0 + c11*b1 + c12*b2) * inv);
        out[2*NFRAMES + t] = (float)((c02*b0 + c12*b1 + c22*b2) * inv);
    }
}

extern "C" void kernel_launch(void* const* d_in, const int* in_sizes, int n_in,
                              void* d_out, int out_size, void* d_ws, size_t ws_size,
                              hipStream_t stream) {
    const float* A  = (const float*)d_in[0];
    const float* B  = (const float*)d_in[1];
    const float* lp = (const float*)d_in[2];
    double* sums = (double*)d_ws;

    dim3 grid((IMG_H - 2*CROP + RPB - 1) / RPB, NFRAMES);  // (32, 32)

    if (ws_size >= (size_t)NFRAMES * NBANDS * 9 * sizeof(double)) {
        // partials path: no memset dispatch, no atomics
        gimbaless_sums<1><<<grid, 256, 0, stream>>>(A, B, lp, sums);
        gimbaless_solve<1><<<1, 64, 0, stream>>>(sums, (float*)d_out);
    } else {
        (void)hipMemsetAsync(d_ws, 0, NFRAMES * 9 * sizeof(double), stream);
        gimbaless_sums<0><<<grid, 256, 0, stream>>>(A, B, lp, sums);
        gimbaless_solve<0><<<1, 64, 0, stream>>>(sums, (float*)d_out);
    }
}

// Round 22
// 77.183 us; speedup vs baseline: 1.0643x; 1.0429x over previous
//
#include <hip/hip_runtime.h>

#define IMG_W 1024
#define IMG_H 1024
#define NFRAMES 32
#define CROP 4
#define RPB 32          // 32 bands x 32 frames = 1024 blocks
#define RING 4          // 4 slots: each staged row fully consumed in one epoch
#define ROWB 4096
#define ABYTES (RING*ROWB)   // 16 KiB per tensor; total 32 KiB -> 4+ blocks/CU

__device__ __forceinline__ void gl_lds16(const float* g, void* l) {
    __builtin_amdgcn_global_load_lds(
        (const __attribute__((address_space(1))) void*)g,
        (__attribute__((address_space(3))) void*)l,
        16, 0, 0);
}

__global__ __launch_bounds__(256) void gimbaless_sums(
    const float* __restrict__ A, const float* __restrict__ B,
    const float* __restrict__ lp9, double* __restrict__ sums)
{
    __shared__ __align__(16) unsigned char smem[2 * ABYTES];

    const int tid  = threadIdx.x;
    const int band = (blockIdx.x & 7) * 4 + (blockIdx.x >> 3);   // XCD swizzle
    const int t    = blockIdx.y;
    const float* a = A + (size_t)t * (IMG_W * IMG_H);
    const float* b = B + (size_t)t * (IMG_W * IMG_H);

    const float lp0 = lp9[0], lp1 = lp9[1], lp2 = lp9[2], lp3 = lp9[3], lp4 = lp9[4];

    const int r0   = CROP + band * RPB;
    const int rend = min(r0 + RPB, IMG_H - CROP);   // even row count

    const int t16 = tid * 16;
    const int wb  = (tid >> 6) * 1024;

    auto stage = [&](int r) {
        const int slot = r & (RING - 1);
        gl_lds16(a + (size_t)r * IMG_W + tid * 4, smem + slot * ROWB + wb);
        gl_lds16(b + (size_t)r * IMG_W + tid * 4, smem + ABYTES + slot * ROWB + wb);
    };
    auto rdA = [&](int slot, int off) -> float4 {
        return *(const float4*)(smem + slot * ROWB + off);
    };
    auto rdB = [&](int slot, int off) -> float4 {
        return *(const float4*)(smem + ABYTES + slot * ROWB + off);
    };

    float s0=0.f,s1=0.f,s2=0.f,s3=0.f,s4=0.f,s5=0.f,s6=0.f,s7=0.f,s8=0.f;
    float d[10][4];   // dif rows h-4 .. h+5
    float av[7][4];   // avg rows h-1 .. h+5
    float cdl[2][4], cdr[2][4], cavl[2], cavr[2];  // CUR halos for rows h, h+1
    const bool active = ((unsigned)(tid - 1) < 254u);
    const int w0 = 4 * tid;
    const float x0 = (float)w0 - 511.5f;

    // ---- prologue wave A: rows r0-4..r0-1 (narrow only) ----
    stage(r0 - 4); stage(r0 - 3); stage(r0 - 2); stage(r0 - 1);
    asm volatile("s_waitcnt vmcnt(0)" ::: "memory");
    if (active) {
#pragma unroll
        for (int k = 0; k < 4; ++k) {
            const int slot = (r0 - 4 + k) & (RING - 1);
            float4 va = rdA(slot, t16);
            float4 vb = rdB(slot, t16);
            d[k][0]=va.x-vb.x; d[k][1]=va.y-vb.y; d[k][2]=va.z-vb.z; d[k][3]=va.w-vb.w;
            if (k == 3) {
                av[0][0]=(va.x+vb.x)*0.5f; av[0][1]=(va.y+vb.y)*0.5f;
                av[0][2]=(va.z+vb.z)*0.5f; av[0][3]=(va.w+vb.w)*0.5f;
            }
        }
    }
    asm volatile("s_waitcnt lgkmcnt(0)" ::: "memory");
    // ---- prologue wave B: rows r0..r0+3 (narrow + halos of r0,r0+1) ----
    stage(r0); stage(r0 + 1); stage(r0 + 2); stage(r0 + 3);
    asm volatile("s_waitcnt vmcnt(0)" ::: "memory");
    __builtin_amdgcn_s_barrier();                 // cross-wave halo visibility
    if (active) {
#pragma unroll
        for (int k = 4; k < 8; ++k) {
            const int slot = (r0 - 4 + k) & (RING - 1);
            float4 va = rdA(slot, t16);
            float4 vb = rdB(slot, t16);
            d[k][0]=va.x-vb.x; d[k][1]=va.y-vb.y; d[k][2]=va.z-vb.z; d[k][3]=va.w-vb.w;
            av[k-3][0]=(va.x+vb.x)*0.5f; av[k-3][1]=(va.y+vb.y)*0.5f;
            av[k-3][2]=(va.z+vb.z)*0.5f; av[k-3][3]=(va.w+vb.w)*0.5f;
        }
#pragma unroll
        for (int rr = 0; rr < 2; ++rr) {          // halos rows r0, r0+1
            const int slot = (r0 + rr) & (RING - 1);
            float4 la = rdA(slot, t16 - 16), lb = rdB(slot, t16 - 16);
            float4 ra = rdA(slot, t16 + 16), rb = rdB(slot, t16 + 16);
            cdl[rr][0]=la.x-lb.x; cdl[rr][1]=la.y-lb.y; cdl[rr][2]=la.z-lb.z; cdl[rr][3]=la.w-lb.w;
            cdr[rr][0]=ra.x-rb.x; cdr[rr][1]=ra.y-rb.y; cdr[rr][2]=ra.z-rb.z; cdr[rr][3]=ra.w-rb.w;
            cavl[rr]=(la.w+lb.w)*0.5f;
            cavr[rr]=(ra.x+rb.x)*0.5f;
        }
    }
    asm volatile("s_waitcnt lgkmcnt(0)" ::: "memory");
    __builtin_amdgcn_s_barrier();                 // all reads done before overwrite
    stage(r0 + 4); stage(r0 + 5);                 // slots of rows r0,r0+1 (consumed)

    // ---- main loop: 2 rows per epoch ----
#pragma unroll 1
    for (int h = r0; h < rend; h += 2) {
        asm volatile("s_waitcnt vmcnt(0)" ::: "memory");  // rows h+4,h+5 arrived
        __builtin_amdgcn_s_barrier();

        const int m4s = h & (RING - 1);          // row h+4
        const int m5s = (h + 1) & (RING - 1);    // row h+5
        const int p2  = (h + 2) & (RING - 1);    // row h+2 (halos now)
        const int p3  = (h + 3) & (RING - 1);    // row h+3

        float4 na0, nb0, na1, nb1, la2, lb2, ra2, rb2, la3, lb3, ra3, rb3;
        if (active) {
            na0 = rdA(m4s, t16);      nb0 = rdB(m4s, t16);
            na1 = rdA(m5s, t16);      nb1 = rdB(m5s, t16);
            la2 = rdA(p2, t16 - 16);  lb2 = rdB(p2, t16 - 16);
            ra2 = rdA(p2, t16 + 16);  rb2 = rdB(p2, t16 + 16);
            la3 = rdA(p3, t16 - 16);  lb3 = rdB(p3, t16 - 16);
            ra3 = rdA(p3, t16 + 16);  rb3 = rdB(p3, t16 + 16);
        }
        asm volatile("s_waitcnt lgkmcnt(0)" ::: "memory");
        __builtin_amdgcn_s_barrier();             // safe to overwrite p2,p3 slots

        if (h + 2 < rend) { stage(h + 6); stage(h + 7); }  // DMA under compute

        if (active) {
            d[8][0]=na0.x-nb0.x; d[8][1]=na0.y-nb0.y; d[8][2]=na0.z-nb0.z; d[8][3]=na0.w-nb0.w;
            av[5][0]=(na0.x+nb0.x)*0.5f; av[5][1]=(na0.y+nb0.y)*0.5f;
            av[5][2]=(na0.z+nb0.z)*0.5f; av[5][3]=(na0.w+nb0.w)*0.5f;
            d[9][0]=na1.x-nb1.x; d[9][1]=na1.y-nb1.y; d[9][2]=na1.z-nb1.z; d[9][3]=na1.w-nb1.w;
            av[6][0]=(na1.x+nb1.x)*0.5f; av[6][1]=(na1.y+nb1.y)*0.5f;
            av[6][2]=(na1.z+nb1.z)*0.5f; av[6][3]=(na1.w+nb1.w)*0.5f;

#pragma unroll
            for (int rr = 0; rr < 2; ++rr) {      // rows h, h+1 with CUR halos
                float dc[12], avc[6];
                dc[0]=cdl[rr][0]; dc[1]=cdl[rr][1]; dc[2]=cdl[rr][2]; dc[3]=cdl[rr][3];
                dc[4]=d[rr+4][0]; dc[5]=d[rr+4][1]; dc[6]=d[rr+4][2]; dc[7]=d[rr+4][3];
                dc[8]=cdr[rr][0]; dc[9]=cdr[rr][1]; dc[10]=cdr[rr][2]; dc[11]=cdr[rr][3];
                avc[0]=cavl[rr];
                avc[1]=av[1+rr][0]; avc[2]=av[1+rr][1]; avc[3]=av[1+rr][2]; avc[4]=av[1+rr][3];
                avc[5]=cavr[rr];

                const float y = (float)(h + rr) - 511.5f;
#pragma unroll
                for (int j = 0; j < 4; ++j) {
                    const float px = (avc[j] - avc[j + 2]) * 0.5f;
                    const float py = (av[rr][j] - av[rr + 2][j]) * 0.5f;
                    float ax = lp4 * dc[j + 4];
                    ax = fmaf(lp0, dc[j] + dc[j + 8], ax);
                    ax = fmaf(lp1, dc[j + 1] + dc[j + 7], ax);
                    ax = fmaf(lp2, dc[j + 2] + dc[j + 6], ax);
                    ax = fmaf(lp3, dc[j + 3] + dc[j + 5], ax);
                    float ay = lp4 * d[rr + 4][j];
                    ay = fmaf(lp0, d[rr][j] + d[rr + 8][j], ay);
                    ay = fmaf(lp1, d[rr + 1][j] + d[rr + 7][j], ay);
                    ay = fmaf(lp2, d[rr + 2][j] + d[rr + 6][j], ay);
                    ay = fmaf(lp3, d[rr + 3][j] + d[rr + 5][j], ay);

                    const float x = x0 + (float)j;
                    const float mom = px * y - py * x;
                    s0 = fmaf(px, px, s0);
                    s1 = fmaf(px, py, s1);
                    s2 = fmaf(px, mom, s2);
                    s3 = fmaf(py, py, s3);
                    s4 = fmaf(py, mom, s4);
                    s5 = fmaf(mom, mom, s5);
                    const float tx = ax * px;
                    const float ty = ay * py;
                    s6 += tx;
                    s7 += ty;
                    s8 += tx * y - ty * x;
                }
            }

            // shift windows by 2
#pragma unroll
            for (int k = 0; k < 8; ++k) {
                d[k][0]=d[k+2][0]; d[k][1]=d[k+2][1]; d[k][2]=d[k+2][2]; d[k][3]=d[k+2][3];
            }
#pragma unroll
            for (int k = 0; k < 5; ++k) {
                av[k][0]=av[k+2][0]; av[k][1]=av[k+2][1]; av[k][2]=av[k+2][2]; av[k][3]=av[k+2][3];
            }
            // CUR <- halos of rows h+2,h+3 (read this epoch)
            cdl[0][0]=la2.x-lb2.x; cdl[0][1]=la2.y-lb2.y; cdl[0][2]=la2.z-lb2.z; cdl[0][3]=la2.w-lb2.w;
            cdr[0][0]=ra2.x-rb2.x; cdr[0][1]=ra2.y-rb2.y; cdr[0][2]=ra2.z-rb2.z; cdr[0][3]=ra2.w-rb2.w;
            cavl[0]=(la2.w+lb2.w)*0.5f; cavr[0]=(ra2.x+rb2.x)*0.5f;
            cdl[1][0]=la3.x-lb3.x; cdl[1][1]=la3.y-lb3.y; cdl[1][2]=la3.z-lb3.z; cdl[1][3]=la3.w-lb3.w;
            cdr[1][0]=ra3.x-rb3.x; cdr[1][1]=ra3.y-rb3.y; cdr[1][2]=ra3.z-rb3.z; cdr[1][3]=ra3.w-rb3.w;
            cavl[1]=(la3.w+lb3.w)*0.5f; cavr[1]=(ra3.x+rb3.x)*0.5f;
        }
    }

    // ---- reduction: f64 wave shuffle -> LDS (aliased) -> global atomic ----
    double ds[9];
    ds[0]=s0; ds[1]=s1; ds[2]=s2; ds[3]=s3; ds[4]=s4;
    ds[5]=s5; ds[6]=s6; ds[7]=s7; ds[8]=s8;
#pragma unroll
    for (int k = 0; k < 9; ++k) {
        double x = ds[k];
        for (int off = 32; off > 0; off >>= 1)
            x += __shfl_down(x, off);
        ds[k] = x;
    }
    __syncthreads();
    double (*red)[9] = (double(*)[9])smem;
    const int wave = tid >> 6, lane = tid & 63;
    if (lane == 0) {
#pragma unroll
        for (int k = 0; k < 9; ++k) red[wave][k] = ds[k];
    }
    __syncthreads();
    if (tid < 9) {
        double tot = red[0][tid] + red[1][tid] + red[2][tid] + red[3][tid];
        atomicAdd(&sums[(size_t)t * 9 + tid], tot);
    }
}

__global__ void gimbaless_solve(const double* __restrict__ sums, float* __restrict__ out)
{
    const int t = threadIdx.x;
    if (t < NFRAMES) {
        const double* s = sums + (size_t)t * 9;
        const double m00=s[0], m01=s[1], m02=s[2], m11=s[3], m12=s[4], m22=s[5];
        const double b0=s[6], b1=s[7], b2=s[8];
        const double c00 = m11*m22 - m12*m12;
        const double c01 = m02*m12 - m01*m22;
        const double c02 = m01*m12 - m02*m11;
        const double c11 = m00*m22 - m02*m02;
        const double c12 = m01*m02 - m00*m12;
        const double c22 = m00*m11 - m01*m01;
        const double det = m00*c00 + m01*c01 + m02*c02;
        const double inv = 1.0 / det;
        out[t]             = (float)((c00*b0 + c01*b1 + c02*b2) * inv);
        out[NFRAMES + t]   = (float)((c01*b0 + c11*b1 + c12*b2) * inv);
        out[2*NFRAMES + t] = (float)((c02*b0 + c12*b1 + c22*b2) * inv);
    }
}

extern "C" void kernel_launch(void* const* d_in, const int* in_sizes, int n_in,
                              void* d_out, int out_size, void* d_ws, size_t ws_size,
                              hipStream_t stream) {
    const float* A  = (const float*)d_in[0];
    const float* B  = (const float*)d_in[1];
    const float* lp = (const float*)d_in[2];
    double* sums = (double*)d_ws;

    (void)hipMemsetAsync(d_ws, 0, NFRAMES * 9 * sizeof(double), stream);

    dim3 grid((IMG_H - 2*CROP + RPB - 1) / RPB, NFRAMES);  // (32, 32)
    gimbaless_sums<<<grid, 256, 0, stream>>>(A, B, lp, sums);
    gimbaless_solve<<<1, 64, 0, stream>>>(sums, (float*)d_out);
}